// Round 6
// baseline (268.736 us; speedup 1.0000x reference)
//
#include <hip/hip_runtime.h>
#include <hip/hip_bf16.h>

#define N_NODES 40000
#define N_EDGES 640000
#define N_FEAT 64
#define HIDDEN 128
#define N_GRAPHS 256
#define CAP 64  // max in-degree (deg ~ Poisson(16); P(>64) ~ 1e-19)
#define SLICE_ELE 1280000  // 40000 rows x 32 cols (ushorts) per slice array

typedef unsigned short ushort_t;
typedef unsigned int uint_t;
typedef __bf16 bf16x8 __attribute__((ext_vector_type(8)));
typedef float f32x4 __attribute__((ext_vector_type(4)));

__device__ inline float b2f_lo(uint_t v) {
  return __builtin_bit_cast(float, v << 16);
}
__device__ inline float b2f_hi(uint_t v) {
  return __builtin_bit_cast(float, v & 0xffff0000u);
}
__device__ inline ushort_t f2b(float f) {
  return __builtin_bit_cast(ushort_t, __float2bfloat16(f));
}
__device__ inline uint_t pack2(float lo, float hi) {
  return (uint_t)f2b(lo) | ((uint_t)f2b(hi) << 16);
}

// ---------------------------------------------------------------------------
// zero: cnt, fillpos, g. Parallel (hipMemsetAsync small-fill = 43us trap).
// ---------------------------------------------------------------------------
__global__ __launch_bounds__(256) void zero_kernel(int* __restrict__ cnt,
                                                   int* __restrict__ fillpos,
                                                   float* __restrict__ g) {
  const int i = blockIdx.x * 256 + threadIdx.x;
  if (i < N_NODES) {
    cnt[i] = 0;
    fillpos[i] = 0;
  }
  if (i < N_GRAPHS * HIDDEN) g[i] = 0.0f;
}

// ---------------------------------------------------------------------------
// prep_main: blocks [0,2500): degree count (atomic).
//            blocks [2500,2852): weight transposes f32[K][128] -> bf16[128][K].
//            blocks [2852,4102): x f32 -> bf16 SLICED [2][40000][32].
// ---------------------------------------------------------------------------
__global__ __launch_bounds__(256) void prep_main_kernel(
    const int* __restrict__ dst, int* __restrict__ cnt,
    const float* __restrict__ W1a, const float* __restrict__ W1b,
    const float* __restrict__ W2a, const float* __restrict__ W2b,
    const float* __restrict__ W3a, const float* __restrict__ W3b,
    const float* __restrict__ x, ushort_t* __restrict__ T1a,
    ushort_t* __restrict__ T1b, ushort_t* __restrict__ T2a,
    ushort_t* __restrict__ T2b, ushort_t* __restrict__ T3a,
    ushort_t* __restrict__ T3b, ushort_t* __restrict__ xs) {
  const int blk = blockIdx.x;
  if (blk < 2500) {
    int e = blk * 256 + threadIdx.x;  // exactly N_EDGES
    atomicAdd(&cnt[dst[e]], 1);
    return;
  }
  if (blk < 2852) {  // weight transposes: 90112 elements
    int i = (blk - 2500) * 256 + threadIdx.x;
    if (i < 8192) {  // W1a: 64x128 -> T1a[128][64]
      int c = i >> 6, k = i & 63;
      T1a[i] = f2b(W1a[k * 128 + c]);
    } else if (i < 24576) {
      int l = i - 8192, c = l >> 7, k = l & 127;
      T1b[l] = f2b(W1b[k * 128 + c]);
    } else if (i < 40960) {
      int l = i - 24576, c = l >> 7, k = l & 127;
      T2a[l] = f2b(W2a[k * 128 + c]);
    } else if (i < 57344) {
      int l = i - 40960, c = l >> 7, k = l & 127;
      T2b[l] = f2b(W2b[k * 128 + c]);
    } else if (i < 73728) {
      int l = i - 57344, c = l >> 7, k = l & 127;
      T3a[l] = f2b(W3a[k * 128 + c]);
    } else if (i < 90112) {
      int l = i - 73728, c = l >> 7, k = l & 127;
      T3b[l] = f2b(W3b[k * 128 + c]);
    }
    return;
  }
  // x: 2,560,000 f32 = 1250 blocks x 256 x 8, sliced write
  const int base = ((blk - 2852) * 256 + threadIdx.x) * 8;
  const float4 v0 = *(const float4*)(x + base);
  const float4 v1 = *(const float4*)(x + base + 4);
  uint4 o;
  o.x = pack2(v0.x, v0.y);
  o.y = pack2(v0.z, v0.w);
  o.z = pack2(v1.x, v1.y);
  o.w = pack2(v1.z, v1.w);
  const int row = base >> 6;
  const int c = base & 63;  // 8-col group: never straddles a 32-col slice
  *(uint4*)(xs + (size_t)(c >> 5) * SLICE_ELE + (size_t)row * 32 + (c & 31)) =
      o;
}

// ---------------------------------------------------------------------------
// scan: rowbase prefix-sum of align8(clamped degree). ONE block, 1024 thr,
// LDS Hillis-Steele over per-thread partials. NO cross-block atomics (R4's
// single-cursor wave-atomics serialized ~100us; this kernel is ~5us).
// Segments 8-aligned so csr16+rowbase is 16B-aligned for uint4 idx loads.
// ---------------------------------------------------------------------------
__global__ __launch_bounds__(1024) void scan_kernel(const int* __restrict__ cnt,
                                                    int* __restrict__ rowbase) {
  __shared__ int psum[1024];
  const int t = threadIdx.x;
  const int i0 = t * 40;  // 1024*40 = 40960 >= N_NODES
  int s = 0;
#pragma unroll 8
  for (int k = 0; k < 40; k++) {
    const int i = i0 + k;
    if (i < N_NODES) {
      int d = cnt[i];
      if (d > CAP) d = CAP;
      s += (d + 7) & ~7;
    }
  }
  psum[t] = s;
  __syncthreads();
  for (int st = 1; st < 1024; st <<= 1) {
    int v = (t >= st) ? psum[t - st] : 0;
    __syncthreads();
    psum[t] += v;
    __syncthreads();
  }
  int run = psum[t] - s;  // exclusive prefix
#pragma unroll 8
  for (int k = 0; k < 40; k++) {
    const int i = i0 + k;
    if (i < N_NODES) {
      int d = cnt[i];
      if (d > CAP) d = CAP;
      rowbase[i] = run;
      run += (d + 7) & ~7;
    }
  }
}

// ---------------------------------------------------------------------------
// fill: scatter edge srcs into compact USHORT CSR (node ids < 40000 < 2^16).
// CSR ~1.6MB vs 10.24MB padded bucket: the sliced gather re-reads idx once
// per slice (x4), so compaction cuts per-layer idx fetch 41MB -> 6.4MB (the
// R5 regression source).
// ---------------------------------------------------------------------------
__global__ __launch_bounds__(256) void fill_kernel(
    const int* __restrict__ src, const int* __restrict__ dst,
    const int* __restrict__ rowbase, int* __restrict__ fillpos,
    ushort_t* __restrict__ csr16) {
  const int e = blockIdx.x * 256 + threadIdx.x;  // exactly N_EDGES
  const int d = dst[e];
  const int p = atomicAdd(&fillpos[d], 1);
  if (p < CAP) csr16[rowbase[d] + p] = (ushort_t)src[e];
}

// ---------------------------------------------------------------------------
// Gather: Z = (1+eps)*H + sum_src H[src], FEATURE-SLICED, XCD-affine.
// H stored as NS separate [40000][32]-col bf16 arrays (64B line-dense rows):
// per-XCD gather footprint = 2.56MB < 4MB L2. s = blk % NS (NS|8) pins each
// round-robin XCD to ONE slice. Idx from compact ushort CSR (uint4 = 8 idx).
// 256 thr = 32 rows x 8 lanes, 8B/lane/edge, 8-deep windows, no LDS.
// Z written in NORMAL [40000][K1] layout (streamed by the MLP).
// ---------------------------------------------------------------------------
template <int K1>
__global__ __launch_bounds__(256, 8) void gather_kernel(
    const ushort_t* __restrict__ Hs, const ushort_t* __restrict__ csr16,
    const int* __restrict__ rowbase, const int* __restrict__ cnt,
    const float* __restrict__ epsP, ushort_t* __restrict__ Z) {
  const int NS = K1 / 32;
  const int tile = blockIdx.x / NS;
  const int s = blockIdx.x % NS;     // (blk%8)%NS -> constant per XCD
  const int grp = threadIdx.x >> 3;  // 0..31: row within tile
  const int l = threadIdx.x & 7;     // lane within row-group
  const int node = tile * 32 + grp;
  const float e1 = 1.0f + *epsP;

  int n = cnt[node];
  if (n > CAP) n = CAP;
  const ushort_t* __restrict__ bl = csr16 + rowbase[node];
  const uint2* __restrict__ hp = (const uint2*)(Hs + (size_t)s * SLICE_ELE);

  float a0 = 0.f, a1 = 0.f, a2 = 0.f, a3 = 0.f;
  int j = 0;
  for (; j + 8 <= n; j += 8) {
    const uint4 iw = *(const uint4*)(bl + j);  // 8 ushort idx
    const uint_t pe[8] = {iw.x & 0xffffu, iw.x >> 16, iw.y & 0xffffu,
                          iw.y >> 16,     iw.z & 0xffffu, iw.z >> 16,
                          iw.w & 0xffffu, iw.w >> 16};
    uint2 v[8];
#pragma unroll
    for (int q = 0; q < 8; q++) v[q] = hp[(size_t)pe[q] * 8 + l];
#pragma unroll
    for (int q = 0; q < 8; q++) {
      a0 += b2f_lo(v[q].x);
      a1 += b2f_hi(v[q].x);
      a2 += b2f_lo(v[q].y);
      a3 += b2f_hi(v[q].y);
    }
  }
  if (j + 4 <= n) {
    const uint2 iw = *(const uint2*)(bl + j);  // 4 ushort idx
    const uint_t pe[4] = {iw.x & 0xffffu, iw.x >> 16, iw.y & 0xffffu,
                          iw.y >> 16};
    uint2 v[4];
#pragma unroll
    for (int q = 0; q < 4; q++) v[q] = hp[(size_t)pe[q] * 8 + l];
#pragma unroll
    for (int q = 0; q < 4; q++) {
      a0 += b2f_lo(v[q].x);
      a1 += b2f_hi(v[q].x);
      a2 += b2f_lo(v[q].y);
      a3 += b2f_hi(v[q].y);
    }
    j += 4;
  }
  for (; j < n; j++) {
    const uint2 v = hp[(size_t)bl[j] * 8 + l];
    a0 += b2f_lo(v.x);
    a1 += b2f_hi(v.x);
    a2 += b2f_lo(v.y);
    a3 += b2f_hi(v.y);
  }
  const uint2 hv = hp[(size_t)node * 8 + l];
  uint2 o;
  o.x = pack2(fmaf(e1, b2f_lo(hv.x), a0), fmaf(e1, b2f_hi(hv.x), a1));
  o.y = pack2(fmaf(e1, b2f_lo(hv.y), a2), fmaf(e1, b2f_hi(hv.y), a3));
  *(uint2*)(Z + (size_t)node * K1 + s * 32 + l * 4) = o;
}

// ---------------------------------------------------------------------------
// MLP: H = relu(relu(Z@Wa+ba)@Wb+bb). 512 thr, BM=32, 1250 blocks.
// Z staged coalesced from NORMAL layout into swizzled LDS; two proven MFMA
// phases; H written SLICED (feeds next gather). POOL pools into g.
// LDS 16KB: Z @0 (swizzled), zts @8192; POOL reuses [0,16KB) as f32 [32][128].
// ---------------------------------------------------------------------------
template <int K1, bool POOL>
__global__ __launch_bounds__(512, 8) void mlp_kernel(
    const ushort_t* __restrict__ Zin, const ushort_t* __restrict__ Ta,
    const float* __restrict__ ba, const ushort_t* __restrict__ Tb,
    const float* __restrict__ bb, ushort_t* __restrict__ Hs_out,
    const int* __restrict__ batch, float* __restrict__ g) {
  __shared__ __align__(16) char smem[16384];
  char* zts = smem + 8192;
  const int tid = threadIdx.x;
  const int wid = tid >> 6;  // 0..7
  const int lane = tid & 63;
  const int l15 = lane & 15;
  const int kg = (lane >> 4) * 8;
  const int crow = (lane >> 4) * 4;
  const int row0 = blockIdx.x * 32;

  // ---- stage Z tile (coalesced) into swizzled LDS ----
  {
    const int row = tid >> 4, l = tid & 15;
    if (K1 == 128) {  // 8KB: one uint4 per thread
      const uint4* __restrict__ zu = (const uint4*)Zin;
      *(uint4*)(smem + ((row * 256 + l * 16) ^ ((row & 7) << 4))) =
          zu[(size_t)(row0 + row) * 16 + l];
    } else {  // K1==64: 4KB: one uint2 per thread (16 uint2 per 128B row)
      const uint2* __restrict__ zu = (const uint2*)Zin;
      *(uint2*)(smem + ((row * 128 + l * 8) ^ ((row & 7) << 4))) =
          zu[(size_t)(row0 + row) * 16 + l];
    }
  }
  __syncthreads();

  // ---- phase 1: zt^T = Ta @ Z^T; wave wid owns zt cols wid*16..+16 ----
  {
    f32x4 acc[2] = {};
#pragma unroll
    for (int kt = 0; kt < K1; kt += 32) {
      bf16x8 a = *(const bf16x8*)(Ta + (size_t)(wid * 16 + l15) * K1 + kt + kg);
      bf16x8 b[2];
#pragma unroll
      for (int nf = 0; nf < 2; nf++) {
        const int R = nf * 16 + l15;
        b[nf] = *(const bf16x8*)(
            smem + ((R * (K1 * 2) + (kt + kg) * 2) ^ ((R & 7) << 4)));
      }
#pragma unroll
      for (int nf = 0; nf < 2; nf++)
        acc[nf] =
            __builtin_amdgcn_mfma_f32_16x16x32_bf16(a, b[nf], acc[nf], 0, 0, 0);
    }
    const int c = wid * 16 + crow;
    const float4 bv = *(const float4*)(ba + c);
#pragma unroll
    for (int nf = 0; nf < 2; nf++) {
      const int m = nf * 16 + l15;
      const f32x4 v = acc[nf];
      uint_t u0 = pack2(fmaxf(v[0] + bv.x, 0.f), fmaxf(v[1] + bv.y, 0.f));
      uint_t u1 = pack2(fmaxf(v[2] + bv.z, 0.f), fmaxf(v[3] + bv.w, 0.f));
      *(uint2*)(zts + ((m * 256 + c * 2) ^ ((m & 7) << 4))) =
          make_uint2(u0, u1);
    }
  }
  __syncthreads();

  // ---- phase 2: H = relu(zt @ Tb + bb); wave = 16 rows x 32 cols ----
  {
    const int wm = wid & 1;
    const int wn = wid >> 1;  // 0..3
    const int col0 = wn * 32;
    f32x4 acc[2] = {};
#pragma unroll
    for (int kt = 0; kt < 128; kt += 32) {
      const int R = wm * 16 + l15;
      bf16x8 a =
          *(const bf16x8*)(zts + ((R * 256 + (kt + kg) * 2) ^ ((R & 7) << 4)));
      bf16x8 b[2];
#pragma unroll
      for (int nf = 0; nf < 2; nf++)
        b[nf] = *(const bf16x8*)(Tb + (size_t)(col0 + nf * 16 + l15) * 128 +
                                 kt + kg);
#pragma unroll
      for (int nf = 0; nf < 2; nf++)
        acc[nf] =
            __builtin_amdgcn_mfma_f32_16x16x32_bf16(a, b[nf], acc[nf], 0, 0, 0);
    }
    if (!POOL) {
#pragma unroll
      for (int nf = 0; nf < 2; nf++) {
        const int cc = col0 + nf * 16 + l15;
        const float bv = bb[cc];
        const f32x4 v = acc[nf];
#pragma unroll
        for (int r = 0; r < 4; r++) {
          float o = fmaxf(v[r] + bv, 0.0f);
          // sliced store: slice cc>>5, col cc&31
          Hs_out[(size_t)(cc >> 5) * SLICE_ELE +
                 (size_t)(row0 + wm * 16 + crow + r) * 32 + (cc & 31)] = f2b(o);
        }
      }
    } else {
      __syncthreads();  // all zts reads done before overwrite
#pragma unroll
      for (int nf = 0; nf < 2; nf++) {
        const int cc = col0 + nf * 16 + l15;
        const float bv = bb[cc];
        const f32x4 v = acc[nf];
#pragma unroll
        for (int r = 0; r < 4; r++) {
          const int R = wm * 16 + crow + r;
          *(float*)(smem + ((R * 512 + cc * 4) ^ ((R & 7) << 4))) =
              fmaxf(v[r] + bv, 0.0f);
        }
      }
      __syncthreads();
      if (tid < 128) {  // thread t owns feature t; batch sorted
        float acc2 = 0.f;
        int cur = batch[row0];
#pragma unroll 4
        for (int r = 0; r < 32; r++) {
          const int bn = batch[row0 + r];
          if (bn != cur) {
            atomicAdd(&g[(size_t)cur * HIDDEN + tid], acc2);
            acc2 = 0.f;
            cur = bn;
          }
          acc2 +=
              *(const float*)(smem + ((r * 512 + tid * 4) ^ ((r & 7) << 4)));
        }
        atomicAdd(&g[(size_t)cur * HIDDEN + tid], acc2);
      }
    }
  }
}

// ---------------------------------------------------------------------------
// Head (f32): out[row] = relu(g[row] @ W1 + b1) @ W2 + b2.
// ---------------------------------------------------------------------------
__global__ __launch_bounds__(128) void head_kernel(
    const float* __restrict__ g, const float* __restrict__ W1,
    const float* __restrict__ b1, const float* __restrict__ W2,
    const float* __restrict__ b2, float* __restrict__ out) {
  const int row = blockIdx.x;
  const int t = threadIdx.x;
  __shared__ float grow[HIDDEN];
  __shared__ float part[2];
  grow[t] = g[(size_t)row * HIDDEN + t];
  __syncthreads();
  float acc = b1[t];
#pragma unroll 8
  for (int k = 0; k < HIDDEN; k++) acc = fmaf(grow[k], W1[k * HIDDEN + t], acc);
  acc = fmaxf(acc, 0.0f);
  float v = acc * W2[t];
#pragma unroll
  for (int off = 32; off > 0; off >>= 1) v += __shfl_down(v, off);
  if ((t & 63) == 0) part[t >> 6] = v;
  __syncthreads();
  if (t == 0) out[row] = part[0] + part[1] + b2[0];
}

// ---------------------------------------------------------------------------
extern "C" void kernel_launch(void* const* d_in, const int* in_sizes, int n_in,
                              void* d_out, int out_size, void* d_ws,
                              size_t ws_size, hipStream_t stream) {
  const float* x = (const float*)d_in[0];
  const int* ei = (const int*)d_in[1];
  const int* src = ei;
  const int* dst = ei + N_EDGES;
  const int* batch = (const int*)d_in[3];
  const float* eps1 = (const float*)d_in[4];
  const float* W1a = (const float*)d_in[5];
  const float* b1a = (const float*)d_in[6];
  const float* W1b = (const float*)d_in[7];
  const float* b1b = (const float*)d_in[8];
  const float* eps2 = (const float*)d_in[9];
  const float* W2a = (const float*)d_in[10];
  const float* b2a = (const float*)d_in[11];
  const float* W2b = (const float*)d_in[12];
  const float* b2b = (const float*)d_in[13];
  const float* eps3 = (const float*)d_in[14];
  const float* W3a = (const float*)d_in[15];
  const float* b3a = (const float*)d_in[16];
  const float* W3b = (const float*)d_in[17];
  const float* b3b = (const float*)d_in[18];
  const float* l1W = (const float*)d_in[19];
  const float* l1b = (const float*)d_in[20];
  const float* l2W = (const float*)d_in[21];
  const float* l2b = (const float*)d_in[22];
  float* out = (float*)d_out;

  // Workspace (36.4MB, same outer slots as the proven layout):
  //   [262144,10502144): csr16 (<=5.12MB) + rowbase + fillpos
  //   xs slot: x sliced [2][40000][32] bf16
  //   hA slot: sliced H (H1s/H2s) [4][40000][32] bf16
  //   hB slot: Z ping-pong (normal layout)
  char* ws = (char*)d_ws;
  int* cnt = (int*)(ws + 0);                      // 160 KB (slot 256K)
  ushort_t* csr16 = (ushort_t*)(ws + 262144);     // <= 5.12 MB
  int* rowbase = (int*)(ws + 5767168);            // 160 KB
  int* fillpos = (int*)(ws + 6029312);            // 160 KB
  ushort_t* xs = (ushort_t*)(ws + 10502144);      // 5.12 MB
  ushort_t* hA = (ushort_t*)(ws + 15622144);      // 10.24 MB (sliced H)
  ushort_t* hB = (ushort_t*)(ws + 25862144);      // 10.24 MB (Z)
  ushort_t* T1a = (ushort_t*)(ws + 36102144);     // 16 KB
  ushort_t* T1b = (ushort_t*)(ws + 36118528);     // 32 KB
  ushort_t* T2a = (ushort_t*)(ws + 36151296);     // 32 KB
  ushort_t* T2b = (ushort_t*)(ws + 36184064);     // 32 KB
  ushort_t* T3a = (ushort_t*)(ws + 36216832);     // 32 KB
  ushort_t* T3b = (ushort_t*)(ws + 36249600);     // 32 KB
  float* g = (float*)(ws + 36282368);             // 128 KB

  zero_kernel<<<157, 256, 0, stream>>>(cnt, fillpos, g);
  prep_main_kernel<<<4102, 256, 0, stream>>>(dst, cnt, W1a, W1b, W2a, W2b, W3a,
                                             W3b, x, T1a, T1b, T2a, T2b, T3a,
                                             T3b, xs);
  scan_kernel<<<1, 1024, 0, stream>>>(cnt, rowbase);
  fill_kernel<<<2500, 256, 0, stream>>>(src, dst, rowbase, fillpos, csr16);

  // Layer 1: gather xs(sliced,NS=2) -> Z1@hB ; mlp Z1 -> H1s@hA
  gather_kernel<64><<<2500, 256, 0, stream>>>(xs, csr16, rowbase, cnt, eps1,
                                              hB);
  mlp_kernel<64, false><<<1250, 512, 0, stream>>>(hB, T1a, b1a, T1b, b1b, hA,
                                                  nullptr, nullptr);
  // Layer 2: gather H1s@hA(NS=4) -> Z2@hB ; mlp Z2 -> H2s@hA
  gather_kernel<128><<<5000, 256, 0, stream>>>(hA, csr16, rowbase, cnt, eps2,
                                               hB);
  mlp_kernel<128, false><<<1250, 512, 0, stream>>>(hB, T2a, b2a, T2b, b2b, hA,
                                                   nullptr, nullptr);
  // Layer 3: gather H2s@hA(NS=4) -> Z3@hB ; mlp Z3 -> pool g
  gather_kernel<128><<<5000, 256, 0, stream>>>(hA, csr16, rowbase, cnt, eps3,
                                               hB);
  mlp_kernel<128, true><<<1250, 512, 0, stream>>>(hB, T3a, b3a, T3b, b3b,
                                                  nullptr, batch, g);

  head_kernel<<<N_GRAPHS, 128, 0, stream>>>(g, l1W, l1b, l2W, l2b, out);
}

// Round 7
// 140.552 us; speedup vs baseline: 1.9120x; 1.9120x over previous
//
#include <hip/hip_runtime.h>
#include <hip/hip_bf16.h>

#define N_NODES 40000
#define N_EDGES 640000
#define N_FEAT 64
#define HIDDEN 128
#define N_GRAPHS 256
#define CAP 64  // max in-degree (deg ~ Poisson(16); P(>64) ~ 1e-19)

typedef unsigned short ushort_t;
typedef unsigned int uint_t;
typedef __bf16 bf16x8 __attribute__((ext_vector_type(8)));
typedef float f32x4 __attribute__((ext_vector_type(4)));

__device__ inline float b2f_lo(uint_t v) {
  return __builtin_bit_cast(float, v << 16);
}
__device__ inline float b2f_hi(uint_t v) {
  return __builtin_bit_cast(float, v & 0xffff0000u);
}
__device__ inline ushort_t f2b(float f) {
  return __builtin_bit_cast(ushort_t, __float2bfloat16(f));
}
__device__ inline uint_t pack2(float lo, float hi) {
  return (uint_t)f2b(lo) | ((uint_t)f2b(hi) << 16);
}

// ---------------------------------------------------------------------------
// zero_cnt: parallel zero of cnt[40000]. (hipMemsetAsync small-fill = 43us
// trap; single-block scans / single-cursor atomics = 77-100us traps.)
// ---------------------------------------------------------------------------
__global__ __launch_bounds__(256) void zero_cnt_kernel(int* __restrict__ cnt) {
  const int i = blockIdx.x * 256 + threadIdx.x;
  if (i < N_NODES) cnt[i] = 0;
}

// ---------------------------------------------------------------------------
// Prep: blocks [0,2500): bucket fill (atomic bump), USHORT ids (<40K<2^16):
//       bucket 5.12MB vs 10.24 -> per-layer idx fetch and fill writes halve.
//       blocks [2500,2852): weight transposes f32[K][128] -> bf16 [128][K].
//       blocks [2852,4102): x f32 -> bf16, VECTORIZED 8 floats/thread.
//       blocks [4102,4230): zero g.
// ---------------------------------------------------------------------------
__global__ __launch_bounds__(256) void prep_kernel(
    const int* __restrict__ src, const int* __restrict__ dst,
    int* __restrict__ cnt, ushort_t* __restrict__ bucket,
    const float* __restrict__ W1a, const float* __restrict__ W1b,
    const float* __restrict__ W2a, const float* __restrict__ W2b,
    const float* __restrict__ W3a, const float* __restrict__ W3b,
    const float* __restrict__ x, ushort_t* __restrict__ T1a,
    ushort_t* __restrict__ T1b, ushort_t* __restrict__ T2a,
    ushort_t* __restrict__ T2b, ushort_t* __restrict__ T3a,
    ushort_t* __restrict__ T3b, ushort_t* __restrict__ xb,
    float* __restrict__ g) {
  const int blk = blockIdx.x;
  if (blk < 2500) {
    int e = blk * 256 + threadIdx.x;  // exactly N_EDGES
    int d = dst[e];
    int pos = atomicAdd(&cnt[d], 1);
    if (pos < CAP) bucket[d * CAP + pos] = (ushort_t)src[e];
    return;
  }
  if (blk < 2852) {  // weight transposes: 90112 elements
    int i = (blk - 2500) * 256 + threadIdx.x;
    if (i < 8192) {  // W1a: 64x128 -> T1a[128][64]
      int c = i >> 6, k = i & 63;
      T1a[i] = f2b(W1a[k * 128 + c]);
    } else if (i < 24576) {
      int l = i - 8192, c = l >> 7, k = l & 127;
      T1b[l] = f2b(W1b[k * 128 + c]);
    } else if (i < 40960) {
      int l = i - 24576, c = l >> 7, k = l & 127;
      T2a[l] = f2b(W2a[k * 128 + c]);
    } else if (i < 57344) {
      int l = i - 40960, c = l >> 7, k = l & 127;
      T2b[l] = f2b(W2b[k * 128 + c]);
    } else if (i < 73728) {
      int l = i - 57344, c = l >> 7, k = l & 127;
      T3a[l] = f2b(W3a[k * 128 + c]);
    } else if (i < 90112) {
      int l = i - 73728, c = l >> 7, k = l & 127;
      T3b[l] = f2b(W3b[k * 128 + c]);
    }
    return;
  }
  if (blk < 4102) {  // x conversion: 2,560,000 f32 = 1250 blocks x 256 x 8
    const int base = ((blk - 2852) * 256 + threadIdx.x) * 8;
    const float4 v0 = *(const float4*)(x + base);
    const float4 v1 = *(const float4*)(x + base + 4);
    uint4 o;
    o.x = pack2(v0.x, v0.y);
    o.y = pack2(v0.z, v0.w);
    o.z = pack2(v1.x, v1.y);
    o.w = pack2(v1.z, v1.w);
    *(uint4*)(xb + base) = o;
    return;
  }
  // zero g: 128 blocks x 256 = 32768 floats exact
  g[(blk - 4102) * 256 + threadIdx.x] = 0.0f;
}

// ---------------------------------------------------------------------------
// Fused GIN layer (the PROVEN R2 structure; slicing/CSR branches all
// regressed -- XCD affinity of blockIdx%N is not real on this dispatcher).
// 512 thr (8 waves), BM=32 nodes/block, 1250 blocks.
// Index staging: block's ushort bucket slice (4 KB) -> LDS, coalesced.
// Gather: 4 rows/wave CONCURRENT (16 lanes/row, uint4 16B/lane for K=128),
// 8-deep unrolled edge loop; ushort indices from LDS.
// Phase 1: zt^T = Ta @ Z^T (wave = 16 zt-cols). Phase 2: H = relu(zt@Tb+bb)
// (wave = 16 rows x 32 cols). POOL variant pools the H tile straight into g.
// LDS 20.5KB: Z tile @0 (swizzled), zts @8192 (swizzled), idx @16384 (4KB);
// POOL reuses [0,16KB) as a f32 [32][128] buffer. Swizzle: byte^=((row&7)<<4).
// ---------------------------------------------------------------------------
template <int K1, bool POOL>
__global__ __launch_bounds__(512, 8) void layer_kernel(
    const ushort_t* __restrict__ Hin, const ushort_t* __restrict__ bucket,
    const int* __restrict__ cnt, const float* __restrict__ epsP,
    const ushort_t* __restrict__ Ta, const float* __restrict__ ba,
    const ushort_t* __restrict__ Tb, const float* __restrict__ bb,
    ushort_t* __restrict__ Hout, const int* __restrict__ batch,
    float* __restrict__ g) {
  __shared__ __align__(16) char smem[20480];
  char* zts = smem + 8192;
  ushort_t* ldsidx = (ushort_t*)(smem + 16384);  // [32][64] ushorts = 4 KB
  const int tid = threadIdx.x;
  const int wid = tid >> 6;  // 0..7
  const int lane = tid & 63;
  const int l15 = lane & 15;
  const int kg = (lane >> 4) * 8;
  const int crow = (lane >> 4) * 4;
  const int row0 = blockIdx.x * 32;
  const float e1 = 1.0f + *epsP;

  // ---- stage this block's bucket slice into LDS (coalesced, uint2/thr) ----
  ((uint2*)ldsidx)[tid] = ((const uint2*)(bucket + row0 * CAP))[tid];
  __syncthreads();

  // ---- gather phase: 4 rows per wave, all concurrent (16 lanes/row) ----
  {
    const int r = wid * 4 + (lane >> 4);  // 0..31
    const int l = lane & 15;
    const int node = row0 + r;
    int n = cnt[node];
    if (n > CAP) n = CAP;
    const ushort_t* __restrict__ bl = ldsidx + r * CAP;
    if (K1 == 128) {
      const uint4* __restrict__ h8 = (const uint4*)Hin;  // 16 uint4 per row
      float a0 = 0.f, a1 = 0.f, a2 = 0.f, a3 = 0.f;
      float a4 = 0.f, a5 = 0.f, a6 = 0.f, a7 = 0.f;
      int j = 0;
      for (; j + 8 <= n; j += 8) {
        const uint4 iw = *(const uint4*)(bl + j);  // 8 ushort idx
        const uint_t pe[8] = {iw.x & 0xffffu, iw.x >> 16, iw.y & 0xffffu,
                              iw.y >> 16,     iw.z & 0xffffu, iw.z >> 16,
                              iw.w & 0xffffu, iw.w >> 16};
        uint4 v[8];
#pragma unroll
        for (int q = 0; q < 8; q++) v[q] = h8[(size_t)pe[q] * 16 + l];
#pragma unroll
        for (int q = 0; q < 8; q++) {
          a0 += b2f_lo(v[q].x);
          a1 += b2f_hi(v[q].x);
          a2 += b2f_lo(v[q].y);
          a3 += b2f_hi(v[q].y);
          a4 += b2f_lo(v[q].z);
          a5 += b2f_hi(v[q].z);
          a6 += b2f_lo(v[q].w);
          a7 += b2f_hi(v[q].w);
        }
      }
      if (j + 4 <= n) {
        const uint2 iw = *(const uint2*)(bl + j);  // 4 ushort idx
        const uint_t pe[4] = {iw.x & 0xffffu, iw.x >> 16, iw.y & 0xffffu,
                              iw.y >> 16};
        uint4 v[4];
#pragma unroll
        for (int q = 0; q < 4; q++) v[q] = h8[(size_t)pe[q] * 16 + l];
#pragma unroll
        for (int q = 0; q < 4; q++) {
          a0 += b2f_lo(v[q].x);
          a1 += b2f_hi(v[q].x);
          a2 += b2f_lo(v[q].y);
          a3 += b2f_hi(v[q].y);
          a4 += b2f_lo(v[q].z);
          a5 += b2f_hi(v[q].z);
          a6 += b2f_lo(v[q].w);
          a7 += b2f_hi(v[q].w);
        }
        j += 4;
      }
      for (; j < n; j++) {
        uint4 v = h8[(size_t)bl[j] * 16 + l];
        a0 += b2f_lo(v.x);
        a1 += b2f_hi(v.x);
        a2 += b2f_lo(v.y);
        a3 += b2f_hi(v.y);
        a4 += b2f_lo(v.z);
        a5 += b2f_hi(v.z);
        a6 += b2f_lo(v.w);
        a7 += b2f_hi(v.w);
      }
      const uint4 hv = h8[(size_t)node * 16 + l];
      uint4 o;
      o.x = pack2(fmaf(e1, b2f_lo(hv.x), a0), fmaf(e1, b2f_hi(hv.x), a1));
      o.y = pack2(fmaf(e1, b2f_lo(hv.y), a2), fmaf(e1, b2f_hi(hv.y), a3));
      o.z = pack2(fmaf(e1, b2f_lo(hv.z), a4), fmaf(e1, b2f_hi(hv.z), a5));
      o.w = pack2(fmaf(e1, b2f_lo(hv.w), a6), fmaf(e1, b2f_hi(hv.w), a7));
      *(uint4*)(smem + ((r * 256 + l * 16) ^ ((r & 7) << 4))) = o;
    } else {  // K1 == 64: row = 128 B = 16 uint2
      const uint2* __restrict__ h4 = (const uint2*)Hin;
      float a0 = 0.f, a1 = 0.f, a2 = 0.f, a3 = 0.f;
      int j = 0;
      for (; j + 8 <= n; j += 8) {
        const uint4 iw = *(const uint4*)(bl + j);
        const uint_t pe[8] = {iw.x & 0xffffu, iw.x >> 16, iw.y & 0xffffu,
                              iw.y >> 16,     iw.z & 0xffffu, iw.z >> 16,
                              iw.w & 0xffffu, iw.w >> 16};
        uint2 v[8];
#pragma unroll
        for (int q = 0; q < 8; q++) v[q] = h4[(size_t)pe[q] * 16 + l];
#pragma unroll
        for (int q = 0; q < 8; q++) {
          a0 += b2f_lo(v[q].x);
          a1 += b2f_hi(v[q].x);
          a2 += b2f_lo(v[q].y);
          a3 += b2f_hi(v[q].y);
        }
      }
      if (j + 4 <= n) {
        const uint2 iw = *(const uint2*)(bl + j);
        const uint_t pe[4] = {iw.x & 0xffffu, iw.x >> 16, iw.y & 0xffffu,
                              iw.y >> 16};
        uint2 v[4];
#pragma unroll
        for (int q = 0; q < 4; q++) v[q] = h4[(size_t)pe[q] * 16 + l];
#pragma unroll
        for (int q = 0; q < 4; q++) {
          a0 += b2f_lo(v[q].x);
          a1 += b2f_hi(v[q].x);
          a2 += b2f_lo(v[q].y);
          a3 += b2f_hi(v[q].y);
        }
        j += 4;
      }
      for (; j < n; j++) {
        uint2 v = h4[(size_t)bl[j] * 16 + l];
        a0 += b2f_lo(v.x);
        a1 += b2f_hi(v.x);
        a2 += b2f_lo(v.y);
        a3 += b2f_hi(v.y);
      }
      const uint2 hv = h4[(size_t)node * 16 + l];
      uint2 o;
      o.x = pack2(fmaf(e1, b2f_lo(hv.x), a0), fmaf(e1, b2f_hi(hv.x), a1));
      o.y = pack2(fmaf(e1, b2f_lo(hv.y), a2), fmaf(e1, b2f_hi(hv.y), a3));
      *(uint2*)(smem + ((r * 128 + l * 8) ^ ((r & 7) << 4))) = o;
    }
  }
  __syncthreads();

  // ---- phase 1: zt^T = Ta @ Z^T; wave wid owns zt cols wid*16..+16 ----
  {
    f32x4 acc[2] = {};
#pragma unroll
    for (int kt = 0; kt < K1; kt += 32) {
      bf16x8 a = *(const bf16x8*)(Ta + (size_t)(wid * 16 + l15) * K1 + kt + kg);
      bf16x8 b[2];
#pragma unroll
      for (int nf = 0; nf < 2; nf++) {
        const int R = nf * 16 + l15;
        b[nf] = *(const bf16x8*)(
            smem + ((R * (K1 * 2) + (kt + kg) * 2) ^ ((R & 7) << 4)));
      }
#pragma unroll
      for (int nf = 0; nf < 2; nf++)
        acc[nf] =
            __builtin_amdgcn_mfma_f32_16x16x32_bf16(a, b[nf], acc[nf], 0, 0, 0);
    }
    // lane holds zt[m][c..c+3]: m = nf*16+l15, c = wid*16+crow
    const int c = wid * 16 + crow;
    const float4 bv = *(const float4*)(ba + c);
#pragma unroll
    for (int nf = 0; nf < 2; nf++) {
      const int m = nf * 16 + l15;
      const f32x4 v = acc[nf];
      uint_t u0 = pack2(fmaxf(v[0] + bv.x, 0.f), fmaxf(v[1] + bv.y, 0.f));
      uint_t u1 = pack2(fmaxf(v[2] + bv.z, 0.f), fmaxf(v[3] + bv.w, 0.f));
      *(uint2*)(zts + ((m * 256 + c * 2) ^ ((m & 7) << 4))) =
          make_uint2(u0, u1);
    }
  }
  __syncthreads();

  // ---- phase 2: H = relu(zt @ Tb + bb); wave = 16 rows x 32 cols ----
  {
    const int wm = wid & 1;
    const int wn = wid >> 1;  // 0..3
    const int col0 = wn * 32;
    f32x4 acc[2] = {};
#pragma unroll
    for (int kt = 0; kt < 128; kt += 32) {
      const int R = wm * 16 + l15;
      bf16x8 a =
          *(const bf16x8*)(zts + ((R * 256 + (kt + kg) * 2) ^ ((R & 7) << 4)));
      bf16x8 b[2];
#pragma unroll
      for (int nf = 0; nf < 2; nf++)
        b[nf] = *(const bf16x8*)(Tb + (size_t)(col0 + nf * 16 + l15) * 128 +
                                 kt + kg);
#pragma unroll
      for (int nf = 0; nf < 2; nf++)
        acc[nf] =
            __builtin_amdgcn_mfma_f32_16x16x32_bf16(a, b[nf], acc[nf], 0, 0, 0);
    }
    if (!POOL) {
#pragma unroll
      for (int nf = 0; nf < 2; nf++) {
        const int cc = col0 + nf * 16 + l15;
        const float bv = bb[cc];
        const f32x4 v = acc[nf];
#pragma unroll
        for (int r = 0; r < 4; r++) {
          float o = fmaxf(v[r] + bv, 0.0f);
          Hout[(size_t)(row0 + wm * 16 + crow + r) * 128 + cc] = f2b(o);
        }
      }
    } else {
      // stage relu(H) tile as f32 into [0,16KB) (Z+zts regions, post-sync)
      __syncthreads();  // all zts reads done before overwrite
#pragma unroll
      for (int nf = 0; nf < 2; nf++) {
        const int cc = col0 + nf * 16 + l15;
        const float bv = bb[cc];
        const f32x4 v = acc[nf];
#pragma unroll
        for (int r = 0; r < 4; r++) {
          const int R = wm * 16 + crow + r;
          *(float*)(smem + ((R * 512 + cc * 4) ^ ((R & 7) << 4))) =
              fmaxf(v[r] + bv, 0.0f);
        }
      }
      __syncthreads();
      if (tid < 128) {  // thread t owns feature t; batch sorted
        float acc2 = 0.f;
        int cur = batch[row0];
#pragma unroll 4
        for (int r = 0; r < 32; r++) {
          const int bn = batch[row0 + r];
          if (bn != cur) {
            atomicAdd(&g[(size_t)cur * HIDDEN + tid], acc2);
            acc2 = 0.f;
            cur = bn;
          }
          acc2 +=
              *(const float*)(smem + ((r * 512 + tid * 4) ^ ((r & 7) << 4)));
        }
        atomicAdd(&g[(size_t)cur * HIDDEN + tid], acc2);
      }
    }
  }
}

// ---------------------------------------------------------------------------
// Head (f32): out[row] = relu(g[row] @ W1 + b1) @ W2 + b2.
// ---------------------------------------------------------------------------
__global__ __launch_bounds__(128) void head_kernel(
    const float* __restrict__ g, const float* __restrict__ W1,
    const float* __restrict__ b1, const float* __restrict__ W2,
    const float* __restrict__ b2, float* __restrict__ out) {
  const int row = blockIdx.x;
  const int t = threadIdx.x;
  __shared__ float grow[HIDDEN];
  __shared__ float part[2];
  grow[t] = g[(size_t)row * HIDDEN + t];
  __syncthreads();
  float acc = b1[t];
#pragma unroll 8
  for (int k = 0; k < HIDDEN; k++) acc = fmaf(grow[k], W1[k * HIDDEN + t], acc);
  acc = fmaxf(acc, 0.0f);
  float v = acc * W2[t];
#pragma unroll
  for (int off = 32; off > 0; off >>= 1) v += __shfl_down(v, off);
  if ((t & 63) == 0) part[t >> 6] = v;
  __syncthreads();
  if (t == 0) out[row] = part[0] + part[1] + b2[0];
}

// ---------------------------------------------------------------------------
extern "C" void kernel_launch(void* const* d_in, const int* in_sizes, int n_in,
                              void* d_out, int out_size, void* d_ws,
                              size_t ws_size, hipStream_t stream) {
  const float* x = (const float*)d_in[0];
  const int* ei = (const int*)d_in[1];
  const int* src = ei;
  const int* dst = ei + N_EDGES;
  const int* batch = (const int*)d_in[3];
  const float* eps1 = (const float*)d_in[4];
  const float* W1a = (const float*)d_in[5];
  const float* b1a = (const float*)d_in[6];
  const float* W1b = (const float*)d_in[7];
  const float* b1b = (const float*)d_in[8];
  const float* eps2 = (const float*)d_in[9];
  const float* W2a = (const float*)d_in[10];
  const float* b2a = (const float*)d_in[11];
  const float* W2b = (const float*)d_in[12];
  const float* b2b = (const float*)d_in[13];
  const float* eps3 = (const float*)d_in[14];
  const float* W3a = (const float*)d_in[15];
  const float* b3a = (const float*)d_in[16];
  const float* W3b = (const float*)d_in[17];
  const float* b3b = (const float*)d_in[18];
  const float* l1W = (const float*)d_in[19];
  const float* l1b = (const float*)d_in[20];
  const float* l2W = (const float*)d_in[21];
  const float* l2b = (const float*)d_in[22];
  float* out = (float*)d_out;

  char* ws = (char*)d_ws;
  int* cnt = (int*)(ws + 0);                      // 160 KB (slot 256K)
  ushort_t* bucket = (ushort_t*)(ws + 262144);    // 5.12 MB (ushort ids)
  ushort_t* xb = (ushort_t*)(ws + 10502144);      // 5.12 MB
  ushort_t* hA = (ushort_t*)(ws + 15622144);      // 10.24 MB
  ushort_t* hB = (ushort_t*)(ws + 25862144);      // 10.24 MB
  ushort_t* T1a = (ushort_t*)(ws + 36102144);     // 16 KB
  ushort_t* T1b = (ushort_t*)(ws + 36118528);     // 32 KB
  ushort_t* T2a = (ushort_t*)(ws + 36151296);     // 32 KB
  ushort_t* T2b = (ushort_t*)(ws + 36184064);     // 32 KB
  ushort_t* T3a = (ushort_t*)(ws + 36216832);     // 32 KB
  ushort_t* T3b = (ushort_t*)(ws + 36249600);     // 32 KB
  float* g = (float*)(ws + 36282368);             // 128 KB

  const int LGRID = N_NODES / 32;  // 1250

  zero_cnt_kernel<<<157, 256, 0, stream>>>(cnt);
  prep_kernel<<<4230, 256, 0, stream>>>(src, dst, cnt, bucket, W1a, W1b, W2a,
                                        W2b, W3a, W3b, x, T1a, T1b, T2a, T2b,
                                        T3a, T3b, xb, g);
  layer_kernel<64, false><<<LGRID, 512, 0, stream>>>(
      xb, bucket, cnt, eps1, T1a, b1a, T1b, b1b, hA, nullptr, nullptr);
  layer_kernel<128, false><<<LGRID, 512, 0, stream>>>(
      hA, bucket, cnt, eps2, T2a, b2a, T2b, b2b, hB, nullptr, nullptr);
  layer_kernel<128, true><<<LGRID, 512, 0, stream>>>(
      hB, bucket, cnt, eps3, T3a, b3a, T3b, b3b, nullptr, batch, g);
  head_kernel<<<N_GRAPHS, 128, 0, stream>>>(g, l1W, l1b, l2W, l2b, out);
}